// Round 9
// baseline (197.319 us; speedup 1.0000x reference)
//
#include <hip/hip_runtime.h>

// LinkPredictor: out[e] = W2 . relu(W1s.z[src] + W1d.z[dst] + b1) + b2
// Factored: C = z @ [W1s|W1d]^T  (node GEMM, bf16 MFMA), then per-edge
// gather + fused add/relu/dot.
// GEMM v8 ("shaped like edge_mlp"): NO LDS, NO barrier. 3125 blocks x 4
// waves; each wave = one (32-row slot, 128-col quarter) task. B frags
// read straight from L2 (Wt = 256 KB, resident); A f32->bf16 in flight.
// Depth-3 triple-buffered prefetch, fully unrolled, issue pinned.

#define NN 100000   // nodes
#define NE 300000   // edges
#define KD 256      // in channels (K)
#define NO 512      // 2*HID output cols (A | B)
#define NSLOT 3125  // 100000 / 32 rows per slot (exact)

typedef __attribute__((ext_vector_type(8))) short short8;
typedef __attribute__((ext_vector_type(8))) unsigned short ushort8;
typedef __attribute__((ext_vector_type(4))) float f32x4;
typedef __attribute__((ext_vector_type(4))) unsigned int uint4v;

__device__ __forceinline__ unsigned short f2bf(float f) {
  union { float f; unsigned int u; } v; v.f = f;
  unsigned int u = v.u;
  u += 0x7fffu + ((u >> 16) & 1u);   // RNE
  return (unsigned short)(u >> 16);
}
__device__ __forceinline__ float bf2f(unsigned short h) {
  union { unsigned int u; float f; } v; v.u = ((unsigned int)h) << 16;
  return v.f;
}
// pack 2 f32 -> {bf16(a) low, bf16(b) high} (round-half-up)
__device__ __forceinline__ unsigned int pkbf(float a, float b) {
  unsigned int ua = __float_as_uint(a) + 0x8000u;
  unsigned int ub = __float_as_uint(b) + 0x8000u;
  return __builtin_amdgcn_perm(ub, ua, 0x07060302u);
}
// stored-col -> hidden-channel permutation (within 0..255)
__device__ __forceinline__ int hperm(int s) {
  int j = s & 127;
  return (s & ~127) + ((j & 7) << 4) + (j >> 3);
}

// ---- repack W1 (f32 [256][512]) -> Wt (bf16 [512][256], K-contiguous) ----
__global__ void prep_w(const float* __restrict__ W1, unsigned short* __restrict__ Wt) {
  int idx = blockIdx.x * 256 + threadIdx.x;   // 512*256 = 131072
  int j = idx >> 8, k = idx & 255;
  float v = (j < 256) ? W1[j * 512 + k] : W1[(j - 256) * 512 + 256 + k];
  Wt[idx] = f2bf(v);
}

// ---- C[n][perm(j)] = sum_k z[n][k] * Wt[j][k] ----
__global__ __launch_bounds__(256, 2) void gemm_zw(const float* __restrict__ z,
                                                  const unsigned short* __restrict__ Wt,
                                                  unsigned short* __restrict__ C) {
  const int s = blockIdx.x;            // slot: 32 rows
  const int t = threadIdx.x;
  const int w = t >> 6, lane = t & 63;
  const int l15 = lane & 15, l4 = lane >> 4;
  const int n0 = w * 128;              // this wave's col quarter

  // A: rows s*32+l15 (band0) and +16 (band1), lane k-base l4*8
  const float* zr = z + ((size_t)s * 32 + l15) * KD + l4 * 8;
  // B frag n: row n0+n*16+l15, same k-base
  const unsigned short* wb = Wt + (size_t)(n0 + l15) * KD + l4 * 8;

#define LOADA(cc, R)                                               \
  R##a = *(const float4*)(zr + (cc) * 32);                         \
  R##b = *(const float4*)(zr + (cc) * 32 + 4);                     \
  R##c = *(const float4*)(zr + 16 * KD + (cc) * 32);               \
  R##d = *(const float4*)(zr + 16 * KD + (cc) * 32 + 4);

#define LOADB(cc, R)                                               \
  { _Pragma("unroll")                                              \
    for (int n = 0; n < 8; ++n)                                    \
      R[n] = *(const ushort8*)(wb + (size_t)n * 16 * KD + (cc) * 32); }

  float4 A0a, A0b, A0c, A0d, A1a, A1b, A1c, A1d, A2a, A2b, A2c, A2d;
  ushort8 B0[8], B1[8], B2[8];

  LOADA(0, A0) LOADB(0, B0)
  LOADA(1, A1) LOADB(1, B1)
  __builtin_amdgcn_sched_barrier(0);

  f32x4 acc0[8], acc1[8];              // zero-init overlaps load latency
#pragma unroll
  for (int n = 0; n < 8; ++n) { acc0[n] = (f32x4)0.f; acc1[n] = (f32x4)0.f; }

#define ITER(kk, AC, BC, APF, BPF, PF)                             \
  {                                                                \
    if (PF) { LOADA((kk) + 2, APF) LOADB((kk) + 2, BPF)            \
              __builtin_amdgcn_sched_barrier(0); }                 \
    union { uint4v u; short8 s; } a0v, a1v;                        \
    a0v.u[0] = pkbf(AC##a.x, AC##a.y); a0v.u[1] = pkbf(AC##a.z, AC##a.w); \
    a0v.u[2] = pkbf(AC##b.x, AC##b.y); a0v.u[3] = pkbf(AC##b.z, AC##b.w); \
    a1v.u[0] = pkbf(AC##c.x, AC##c.y); a1v.u[1] = pkbf(AC##c.z, AC##c.w); \
    a1v.u[2] = pkbf(AC##d.x, AC##d.y); a1v.u[3] = pkbf(AC##d.z, AC##d.w); \
    _Pragma("unroll")                                              \
    for (int n = 0; n < 8; ++n) {                                  \
      union { ushort8 u; short8 s; } bv; bv.u = BC[n];             \
      acc0[n] = __builtin_amdgcn_mfma_f32_16x16x32_bf16(a0v.s, bv.s, acc0[n], 0, 0, 0); \
      acc1[n] = __builtin_amdgcn_mfma_f32_16x16x32_bf16(a1v.s, bv.s, acc1[n], 0, 0, 0); \
    }                                                              \
  }

  ITER(0, A0, B0, A2, B2, 1)
  ITER(1, A1, B1, A0, B0, 1)
  ITER(2, A2, B2, A1, B1, 1)
  ITER(3, A0, B0, A2, B2, 1)
  ITER(4, A1, B1, A0, B0, 1)
  ITER(5, A2, B2, A1, B1, 1)
  ITER(6, A0, B0, A0, B0, 0)
  ITER(7, A1, B1, A1, B1, 0)
#undef ITER
#undef LOADA
#undef LOADB

  // epilogue: one 16B store per lane per row, permuted cols j = l15*8+n
#pragma unroll
  for (int r = 0; r < 4; ++r) {
    uint4v p;
    p[0] = pkbf(acc0[0][r], acc0[1][r]); p[1] = pkbf(acc0[2][r], acc0[3][r]);
    p[2] = pkbf(acc0[4][r], acc0[5][r]); p[3] = pkbf(acc0[6][r], acc0[7][r]);
    *(uint4v*)(C + ((size_t)s * 32 + l4 * 4 + r) * NO + n0 + l15 * 8) = p;
    p[0] = pkbf(acc1[0][r], acc1[1][r]); p[1] = pkbf(acc1[2][r], acc1[3][r]);
    p[2] = pkbf(acc1[4][r], acc1[5][r]); p[3] = pkbf(acc1[6][r], acc1[7][r]);
    *(uint4v*)(C + ((size_t)s * 32 + 16 + l4 * 4 + r) * NO + n0 + l15 * 8) = p;
  }
}

// ---- per-edge: out[e] = b2 + sum W2[h]*relu(A[s][h] + B[d][h] + b1[h]) ----
// C cols are permuted; load b1/W2 through hperm to match.
__global__ __launch_bounds__(256) void edge_mlp(const unsigned short* __restrict__ C,
                                                const int* __restrict__ ei,
                                                const float* __restrict__ b1,
                                                const float* __restrict__ W2,
                                                const float* __restrict__ b2,
                                                float* __restrict__ out) {
  const int t = threadIdx.x;
  const int lane = t & 63;
  const int g = lane >> 4;           // edge slot within wave (0..3)
  const int c0 = (lane & 15) * 16;   // stored-channel base for this lane
  float b1v[16], w2v[16];
#pragma unroll
  for (int i = 0; i < 16; ++i) {
    const int h = hperm(c0 + i);
    b1v[i] = b1[h]; w2v[i] = W2[h];
  }
  const float bias2 = b2[0];
  const int waveId = blockIdx.x * 4 + (t >> 6);
  const int nw = gridDim.x * 4;
  for (int e0 = waveId * 4; e0 < NE; e0 += nw * 4) {
    const int e = e0 + g;                 // NE % 4 == 0 -> always valid
    const int sn = ei[e];
    const int dn = ei[NE + e];
    const ushort8* ap = (const ushort8*)(C + (size_t)sn * NO + c0);
    const ushort8* bp = (const ushort8*)(C + (size_t)dn * NO + 256 + c0);
    ushort8 a0 = ap[0], a1 = ap[1];
    ushort8 v0 = bp[0], v1 = bp[1];
    float partial = 0.f;
#pragma unroll
    for (int j = 0; j < 8; ++j) {
      float h = bf2f(a0[j]) + bf2f(v0[j]) + b1v[j];
      h = fmaxf(h, 0.f);
      partial = fmaf(h, w2v[j], partial);
    }
#pragma unroll
    for (int j = 0; j < 8; ++j) {
      float h = bf2f(a1[j]) + bf2f(v1[j]) + b1v[8 + j];
      h = fmaxf(h, 0.f);
      partial = fmaf(h, w2v[8 + j], partial);
    }
    partial += __shfl_xor(partial, 8);
    partial += __shfl_xor(partial, 4);
    partial += __shfl_xor(partial, 2);
    partial += __shfl_xor(partial, 1);
    if ((lane & 15) == 0) out[e] = partial + bias2;
  }
}

extern "C" void kernel_launch(void* const* d_in, const int* in_sizes, int n_in,
                              void* d_out, int out_size, void* d_ws, size_t ws_size,
                              hipStream_t stream) {
  const float* z  = (const float*)d_in[0];
  const float* W1 = (const float*)d_in[1];
  const float* b1 = (const float*)d_in[2];
  const float* W2 = (const float*)d_in[3];
  const float* b2 = (const float*)d_in[4];
  const int*   ei = (const int*)d_in[5];
  float* out = (float*)d_out;

  unsigned short* C  = (unsigned short*)d_ws;          // 100000*512 bf16 = 102.4 MB
  unsigned short* Wt = C + (size_t)NN * NO;            // 512*256 bf16 = 256 KB

  prep_w<<<512, 256, 0, stream>>>(W1, Wt);
  gemm_zw<<<NSLOT, 256, 0, stream>>>(z, Wt, C);
  edge_mlp<<<2048, 256, 0, stream>>>(C, ei, b1, W2, b2, out);
}

// Round 10
// 126.420 us; speedup vs baseline: 1.5608x; 1.5608x over previous
//
#include <hip/hip_runtime.h>

// LinkPredictor: out[e] = W2 . relu(W1s.z[src] + W1d.z[dst] + b1) + b2
// Factored: C = z @ [W1s|W1d]^T  (node GEMM, bf16 MFMA), then per-edge
// gather + fused add/relu/dot.
// GEMM v10 (operand-transposed): D = Wt_frag x z_frag. Wt quarter staged
// once in LDS (64 KB swizzled); z packs straight from global into the
// MFMA B-operand (no staging, tiny live set); 2-deep named prefetch.
// D-col = node, D-row = wt-col -> natural-layout contiguous stores.

#define NN 100000   // nodes (3125 slots of 32, exact)
#define NE 300000   // edges
#define KD 256      // in channels (K)
#define NO 512      // 2*HID output cols (A | B)

typedef __attribute__((ext_vector_type(8))) short short8;
typedef __attribute__((ext_vector_type(8))) unsigned short ushort8;
typedef __attribute__((ext_vector_type(4))) float f32x4;
typedef __attribute__((ext_vector_type(4))) unsigned int uint4v;

__device__ __forceinline__ unsigned short f2bf(float f) {
  union { float f; unsigned int u; } v; v.f = f;
  unsigned int u = v.u;
  u += 0x7fffu + ((u >> 16) & 1u);   // RNE
  return (unsigned short)(u >> 16);
}
__device__ __forceinline__ float bf2f(unsigned short h) {
  union { unsigned int u; float f; } v; v.u = ((unsigned int)h) << 16;
  return v.f;
}
// pack 2 f32 -> {bf16(a) low, bf16(b) high} (round-half-up)
__device__ __forceinline__ unsigned int pkbf(float a, float b) {
  unsigned int ua = __float_as_uint(a) + 0x8000u;
  unsigned int ub = __float_as_uint(b) + 0x8000u;
  return __builtin_amdgcn_perm(ub, ua, 0x07060302u);
}

// ---- repack W1 (f32 [256][512]) -> Wt (bf16 [512][256], K-contiguous) ----
__global__ void prep_w(const float* __restrict__ W1, unsigned short* __restrict__ Wt) {
  int idx = blockIdx.x * 256 + threadIdx.x;   // 512*256 = 131072
  int j = idx >> 8, k = idx & 255;
  float v = (j < 256) ? W1[j * 512 + k] : W1[(j - 256) * 512 + 256 + k];
  Wt[idx] = f2bf(v);
}

// ---- C[n][j] = sum_k z[n][k] * Wt[j][k]  (natural layout) ----
__global__ __launch_bounds__(256, 2) void gemm_zw(const float* __restrict__ z,
                                                  const unsigned short* __restrict__ Wt,
                                                  unsigned short* __restrict__ C) {
  __shared__ unsigned short Bs[128 * KD];   // 64 KB: Wt quarter, swizzled

  // XCD-pinned: 4 quarter-siblings of one m-group share blockIdx&7
  const int b = blockIdx.x;            // 0..3135
  const int xcd = b & 7;
  const int rr = b >> 3;               // 0..391
  const int q = rr & 3;                // col quarter
  const int g = (rr >> 2) * 8 + xcd;   // m-group 0..783
  if (g >= 782) return;
  const int n0 = q * 128;

  const int t = threadIdx.x;
  const int w = t >> 6, lane = t & 63;
  const int l15 = lane & 15, l4 = lane >> 4;

  // ---- stage Wt quarter: row r (0..127), 16B chunk c stored at c^(r&7)
#pragma unroll
  for (int i = 0; i < 16; ++i) {
    const int id = t + 256 * i;        // 0..4095 chunks
    const int row = id >> 5, c = id & 31;
    ushort8 v = *(const ushort8*)(Wt + (size_t)(n0 + row) * KD + c * 8);
    *(ushort8*)&Bs[row * KD + ((c ^ (row & 7)) << 3)] = v;
  }
  __syncthreads();                     // the ONLY barrier

  const int slot = g * 4 + w;          // 32-node slot
  if (slot >= 3125) return;            // 3 tail waves idle
  const int node0 = slot * 32;

  // z: band0 row node0+l15, band1 +16; lane k-base l4*8
  const float* zr = z + (size_t)(node0 + l15) * KD + l4 * 8;

#define LOADZ(kc, Ra, Rb, Rc, Rd)                                  \
  Ra = *(const float4*)(zr + (kc) * 32);                           \
  Rb = *(const float4*)(zr + (kc) * 32 + 4);                       \
  Rc = *(const float4*)(zr + 16 * KD + (kc) * 32);                 \
  Rd = *(const float4*)(zr + 16 * KD + (kc) * 32 + 4);

  float4 Z0a, Z0b, Z0c, Z0d, Z1a, Z1b, Z1c, Z1d;
  LOADZ(0, Z0a, Z0b, Z0c, Z0d)
  LOADZ(1, Z1a, Z1b, Z1c, Z1d)
  __builtin_amdgcn_sched_barrier(0);

  f32x4 acc0[8], acc1[8];
#pragma unroll
  for (int f = 0; f < 8; ++f) { acc0[f] = (f32x4)0.f; acc1[f] = (f32x4)0.f; }

  // per k-step: pack (consume buf) -> refill buf (kc+2) -> 8 wt-frags x 2 MFMA
#define KSTEP(kc, Ra, Rb, Rc, Rd, PF)                                   \
  {                                                                     \
    union { uint4v u; short8 s; } zb0, zb1;                             \
    zb0.u[0] = pkbf(Ra.x, Ra.y); zb0.u[1] = pkbf(Ra.z, Ra.w);           \
    zb0.u[2] = pkbf(Rb.x, Rb.y); zb0.u[3] = pkbf(Rb.z, Rb.w);           \
    zb1.u[0] = pkbf(Rc.x, Rc.y); zb1.u[1] = pkbf(Rc.z, Rc.w);           \
    zb1.u[2] = pkbf(Rd.x, Rd.y); zb1.u[3] = pkbf(Rd.z, Rd.w);           \
    if (PF) { LOADZ((kc) + 2, Ra, Rb, Rc, Rd)                           \
              __builtin_amdgcn_sched_barrier(0); }                      \
    _Pragma("unroll")                                                   \
    for (int f = 0; f < 8; ++f) {                                       \
      union { ushort8 u; short8 s; } wv;                                \
      wv.u = *(const ushort8*)&Bs[(f * 16 + l15) * KD +                 \
                                  ((((kc) * 4 + l4) ^ (l15 & 7)) << 3)];\
      acc0[f] = __builtin_amdgcn_mfma_f32_16x16x32_bf16(wv.s, zb0.s, acc0[f], 0, 0, 0); \
      acc1[f] = __builtin_amdgcn_mfma_f32_16x16x32_bf16(wv.s, zb1.s, acc1[f], 0, 0, 0); \
    }                                                                   \
  }

  KSTEP(0, Z0a, Z0b, Z0c, Z0d, 1)
  KSTEP(1, Z1a, Z1b, Z1c, Z1d, 1)
  KSTEP(2, Z0a, Z0b, Z0c, Z0d, 1)
  KSTEP(3, Z1a, Z1b, Z1c, Z1d, 1)
  KSTEP(4, Z0a, Z0b, Z0c, Z0d, 1)
  KSTEP(5, Z1a, Z1b, Z1c, Z1d, 1)
  KSTEP(6, Z0a, Z0b, Z0c, Z0d, 0)
  KSTEP(7, Z1a, Z1b, Z1c, Z1d, 0)
#undef KSTEP
#undef LOADZ

  // store: lane holds node (l15/band) x wt-cols {n0+f*16+l4*4+0..3}
#pragma unroll
  for (int f = 0; f < 8; ++f) {
    uint2 p;
    p.x = pkbf(acc0[f][0], acc0[f][1]);
    p.y = pkbf(acc0[f][2], acc0[f][3]);
    *(uint2*)(C + (size_t)(node0 + l15) * NO + n0 + f * 16 + l4 * 4) = p;
    p.x = pkbf(acc1[f][0], acc1[f][1]);
    p.y = pkbf(acc1[f][2], acc1[f][3]);
    *(uint2*)(C + (size_t)(node0 + 16 + l15) * NO + n0 + f * 16 + l4 * 4) = p;
  }
}

// ---- per-edge: out[e] = b2 + sum W2[h]*relu(A[s][h] + B[d][h] + b1[h]) ----
// C is natural-layout now (no permutation).
__global__ __launch_bounds__(256) void edge_mlp(const unsigned short* __restrict__ C,
                                                const int* __restrict__ ei,
                                                const float* __restrict__ b1,
                                                const float* __restrict__ W2,
                                                const float* __restrict__ b2,
                                                float* __restrict__ out) {
  const int t = threadIdx.x;
  const int lane = t & 63;
  const int g = lane >> 4;           // edge slot within wave (0..3)
  const int c0 = (lane & 15) * 16;   // channel base for this lane
  float b1v[16], w2v[16];
#pragma unroll
  for (int i = 0; i < 16; ++i) { b1v[i] = b1[c0 + i]; w2v[i] = W2[c0 + i]; }
  const float bias2 = b2[0];
  const int waveId = blockIdx.x * 4 + (t >> 6);
  const int nw = gridDim.x * 4;
  for (int e0 = waveId * 4; e0 < NE; e0 += nw * 4) {
    const int e = e0 + g;                 // NE % 4 == 0 -> always valid
    const int sn = ei[e];
    const int dn = ei[NE + e];
    const ushort8* ap = (const ushort8*)(C + (size_t)sn * NO + c0);
    const ushort8* bp = (const ushort8*)(C + (size_t)dn * NO + 256 + c0);
    ushort8 a0 = ap[0], a1 = ap[1];
    ushort8 v0 = bp[0], v1 = bp[1];
    float partial = 0.f;
#pragma unroll
    for (int j = 0; j < 8; ++j) {
      float h = bf2f(a0[j]) + bf2f(v0[j]) + b1v[j];
      h = fmaxf(h, 0.f);
      partial = fmaf(h, w2v[j], partial);
    }
#pragma unroll
    for (int j = 0; j < 8; ++j) {
      float h = bf2f(a1[j]) + bf2f(v1[j]) + b1v[8 + j];
      h = fmaxf(h, 0.f);
      partial = fmaf(h, w2v[8 + j], partial);
    }
    partial += __shfl_xor(partial, 8);
    partial += __shfl_xor(partial, 4);
    partial += __shfl_xor(partial, 2);
    partial += __shfl_xor(partial, 1);
    if ((lane & 15) == 0) out[e] = partial + bias2;
  }
}

extern "C" void kernel_launch(void* const* d_in, const int* in_sizes, int n_in,
                              void* d_out, int out_size, void* d_ws, size_t ws_size,
                              hipStream_t stream) {
  const float* z  = (const float*)d_in[0];
  const float* W1 = (const float*)d_in[1];
  const float* b1 = (const float*)d_in[2];
  const float* W2 = (const float*)d_in[3];
  const float* b2 = (const float*)d_in[4];
  const int*   ei = (const int*)d_in[5];
  float* out = (float*)d_out;

  unsigned short* C  = (unsigned short*)d_ws;          // 100000*512 bf16 = 102.4 MB
  unsigned short* Wt = C + (size_t)NN * NO;            // 512*256 bf16 = 256 KB

  prep_w<<<512, 256, 0, stream>>>(W1, Wt);
  // 98 gdiv x 4 quarters x 8 xcds = 3136 blocks (g>=782 idle)
  gemm_zw<<<3136, 256, 0, stream>>>(z, Wt, C);
  edge_mlp<<<2048, 256, 0, stream>>>(C, ei, b1, W2, b2, out);
}